// Round 4
// baseline (292.926 us; speedup 1.0000x reference)
//
#include <hip/hip_runtime.h>

// x:  [32,16,1,2048] int32 -> 1,048,576 tokens
// W:  [64, 4096] fp32,  b: [64] fp32
// out:[32,16,2048,64] fp32 = 256 MiB  -> write-BW-bound, floor ~42 us @6.5 TB/s
#define VOCAB   4096
#define F_DIM   64
#define TOKENS  (32 * 16 * 2048)

typedef float f32x4 __attribute__((ext_vector_type(4)));

// Step 1: WT[v][f] = W[f][v] + b[f], via LDS 64x64 tile transpose.
// Both the W read and the WT write are fully coalesced; +1 pad kills the
// bank conflict on the transposed LDS read.
__global__ void build_wt_kernel(const float* __restrict__ W,
                                const float* __restrict__ bias,
                                float* __restrict__ WT) {
    __shared__ float tile[F_DIM][F_DIM + 1];   // 64 x 65 floats
    const int t  = threadIdx.x;                 // 0..255
    const int v0 = blockIdx.x * F_DIM;          // 64 v-values per block

    // Read: linear = f*64 + dv, consecutive t -> consecutive dv (coalesced).
    #pragma unroll
    for (int i = 0; i < 16; ++i) {
        int linear = i * 256 + t;
        int f  = linear >> 6;
        int dv = linear & 63;
        tile[f][dv] = W[f * VOCAB + v0 + dv];
    }
    __syncthreads();

    // Write: linear = dv*64 + f, consecutive t -> consecutive f (coalesced).
    #pragma unroll
    for (int i = 0; i < 16; ++i) {
        int linear = i * 256 + t;
        int dv = linear >> 6;
        int f  = linear & 63;
        WT[(v0 + dv) * F_DIM + f] = tile[f][dv] + bias[f];
    }
}

// Step 2: gather. 16 lanes per token, one float4 each -> every wave writes
// 1 KiB contiguous and reads 4 contiguous 256 B rows of WT (L2-resident).
// Plain stores (write-back L2 path = the 6.5 TB/s fillBuffer path).
__global__ void __launch_bounds__(256)
gather_kernel(const int* __restrict__ idx,
              const f32x4* __restrict__ WT4,
              f32x4* __restrict__ out4) {
    const unsigned nthreads = gridDim.x * blockDim.x;
    const unsigned total    = (unsigned)TOKENS * 16u;   // 16,777,216 float4s
    for (unsigned i = blockIdx.x * blockDim.x + threadIdx.x; i < total;
         i += nthreads) {
        unsigned token = i >> 4;
        unsigned q     = i & 15;
        int id = idx[token];
        out4[i] = WT4[(unsigned)id * 16u + q];
    }
}

extern "C" void kernel_launch(void* const* d_in, const int* in_sizes, int n_in,
                              void* d_out, int out_size, void* d_ws, size_t ws_size,
                              hipStream_t stream) {
    const int*   x = (const int*)d_in[0];
    const float* W = (const float*)d_in[1];
    const float* b = (const float*)d_in[2];
    float* out = (float*)d_out;
    float* WT  = (float*)d_ws;   // VOCAB*F_DIM floats = 1 MiB scratch

    build_wt_kernel<<<VOCAB / F_DIM, 256, 0, stream>>>(W, b, WT);

    // 4096 blocks x 256 thr = 1,048,576 threads, 16 float4 each (grid-stride).
    gather_kernel<<<4096, 256, 0, stream>>>(x, (const f32x4*)WT, (f32x4*)out);
}

// Round 7
// 268.406 us; speedup vs baseline: 1.0914x; 1.0914x over previous
//
#include <hip/hip_runtime.h>

// x:  [32,16,1,2048] int32 -> 1,048,576 tokens
// W:  [64, 4096] fp32,  b: [64] fp32
// out:[32,16,2048,64] fp32 = 256 MiB write. Gather floor ~47 us @6.5 TB/s.
// R2/R4: 287us == 293us across NT/block/build variants. Two live theories:
//  (a) harness poison fills (1GiB d_ws @165us + 268MB d_out @42us) are inside
//      the timed region -> fixed ~207us; our kernels ~80us of the total.
//  (b) single dependent idx->WT chain per thread -> latency-bound gather.
// This round attacks (b) with MLP=8 and will disambiguate (a) by arithmetic.
#define VOCAB   4096
#define F_DIM   64
#define TOKENS  (32 * 16 * 2048)

typedef float f32x4 __attribute__((ext_vector_type(4)));

// Build WT[v][f] = W[f][v] + b[f].  65,536 threads = 256 blocks.
// Reads: 4 coalesced streams (consecutive lanes -> consecutive v).
// Writes: 16 B per thread at 256 B stride -> imperfect but only 1 MiB total.
__global__ void build_wt_kernel(const float* __restrict__ W,
                                const float* __restrict__ bias,
                                f32x4* __restrict__ WT4) {
    int k  = blockIdx.x * blockDim.x + threadIdx.x;   // 0..65535
    int f4 = k >> 12;                                 // 0..15
    int v  = k & (VOCAB - 1);
    int f  = f4 * 4;
    f32x4 r;
    r.x = W[(f + 0) * VOCAB + v] + bias[f + 0];
    r.y = W[(f + 1) * VOCAB + v] + bias[f + 1];
    r.z = W[(f + 2) * VOCAB + v] + bias[f + 2];
    r.w = W[(f + 3) * VOCAB + v] + bias[f + 3];
    WT4[v * 16 + f4] = r;
}

// Gather. Fragment = one float4 (16 B); 16 fragments per token.
// 16,777,216 fragments; each thread owns 8, spaced nth apart ->
// 8 INDEPENDENT idx->WT->out chains (MLP=8 vs 1 in R2).
// Fully-unrolled arrays => static register indexing (no scratch).
// Every wave-store instr: 64 consecutive float4 = 1 KiB contiguous.
__global__ void __launch_bounds__(256)
gather_kernel(const int* __restrict__ idx,
              const f32x4* __restrict__ WT4,
              f32x4* __restrict__ out4) {
    const unsigned nth = gridDim.x * blockDim.x;      // 2,097,152
    const unsigned tid = blockIdx.x * blockDim.x + threadIdx.x;

    unsigned i[8];
    #pragma unroll
    for (int k = 0; k < 8; ++k) i[k] = tid + (unsigned)k * nth;

    // All idx loads issued first (independent; 16 lanes share one token).
    int id[8];
    #pragma unroll
    for (int k = 0; k < 8; ++k) id[k] = idx[i[k] >> 4];

    // All WT gathers issued next (independent of each other).
    f32x4 v[8];
    #pragma unroll
    for (int k = 0; k < 8; ++k)
        v[k] = WT4[(unsigned)id[k] * 16u + (i[k] & 15u)];

    // Coalesced stores.
    #pragma unroll
    for (int k = 0; k < 8; ++k) out4[i[k]] = v[k];
}

extern "C" void kernel_launch(void* const* d_in, const int* in_sizes, int n_in,
                              void* d_out, int out_size, void* d_ws, size_t ws_size,
                              hipStream_t stream) {
    const int*   x = (const int*)d_in[0];
    const float* W = (const float*)d_in[1];
    const float* b = (const float*)d_in[2];
    float* out = (float*)d_out;
    float* WT  = (float*)d_ws;   // 1 MiB scratch

    build_wt_kernel<<<256, 256, 0, stream>>>(W, b, (f32x4*)WT);

    // 8192 blocks x 256 thr; 8 float4 fragments per thread (exact cover).
    gather_kernel<<<8192, 256, 0, stream>>>(x, (const f32x4*)WT, (f32x4*)out);
}